// Round 4
// baseline (187.632 us; speedup 1.0000x reference)
//
#include <hip/hip_runtime.h>

#define B_SZ   8
#define SEQ    2048
#define PSEQ   (SEQ+16)     // 16 zero pad rows before each batch
#define SDIM   1024
#define DIN    512
#define DOUT   512
#define KX     10
#define RTOT   (B_SZ*SEQ)   // 16384
#define LC     64
#define NC     (SEQ/LC)     // 32

typedef __attribute__((ext_vector_type(8))) short short8;
typedef __attribute__((ext_vector_type(4))) float f32x4;
typedef __attribute__((ext_vector_type(4))) unsigned short bfx4;

// ---- workspace layout (bytes) ----
#define OFF_XP   0UL             // B_SZ*PSEQ*DIN*2      = 16,908,288
#define OFF_UB   16908288UL      // RTOT*SDIM*2 (bf16)   = 33,554,432
#define OFF_HS   50462720UL      // RTOT*SDIM*2 (bf16)   = 33,554,432
#define OFF_BT   84017152UL      // SDIM*DIN*2           = 1,048,576
#define OFF_CT   85065728UL      // DOUT*SDIM*2          = 1,048,576
#define OFF_MT   86114304UL      // KX*DOUT*DIN*2        = 5,242,880
// total ws: 91,357,184 bytes.  E/Sb live in d_out (overwritten by k_gemm_out).

__device__ __forceinline__ short f2bf(float f) {
  unsigned u = __builtin_bit_cast(unsigned, f);
  u += 0x7fffu + ((u >> 16) & 1u);   // RNE
  return (short)(u >> 16);
}
__device__ __forceinline__ float bf2f(unsigned short b) {
  return __builtin_bit_cast(float, (unsigned)b << 16);
}

#define GLOAD16(gp, lp) __builtin_amdgcn_global_load_lds( \
    (const __attribute__((address_space(1))) void*)(gp), \
    (__attribute__((address_space(3))) void*)(lp), 16, 0, 0)

// ================= conversion / prep =================
__global__ void k_conv_x(const float* __restrict__ in, short* __restrict__ out) {
  const int NG = RTOT * (DIN / 8);
  for (int g = blockIdx.x * 256 + threadIdx.x; g < NG; g += 2048 * 256) {
    int r = g >> 6, c8 = g & 63;
    int b = r >> 11, t = r & 2047;
    const float4* p = reinterpret_cast<const float4*>(in) + (size_t)g * 2;
    float4 f0 = p[0], f1 = p[1];
    short8 o;
    o[0]=f2bf(f0.x); o[1]=f2bf(f0.y); o[2]=f2bf(f0.z); o[3]=f2bf(f0.w);
    o[4]=f2bf(f1.x); o[5]=f2bf(f1.y); o[6]=f2bf(f1.z); o[7]=f2bf(f1.w);
    *reinterpret_cast<short8*>(out + ((size_t)(b * PSEQ + 16 + t) * DIN + c8 * 8)) = o;
  }
}

__global__ void k_zero_pad(short* __restrict__ Xp) {
  int idx = blockIdx.x * 256 + threadIdx.x;
  if (idx >= B_SZ * 16 * (DIN / 8)) return;
  int b = idx >> 10, rem = idx & 1023;
  int row16 = rem >> 6, c8 = rem & 63;
  const short8 z = {0,0,0,0,0,0,0,0};
  *reinterpret_cast<short8*>(Xp + ((size_t)(b * PSEQ + row16) * DIN + c8 * 8)) = z;
}

__global__ void k_transpose_bf16(const float* __restrict__ in, short* __restrict__ out,
                                 int rows, int cols) {
  __shared__ float t[32][33];
  int bx = blockIdx.x * 32, by = blockIdx.y * 32;
  int tx = threadIdx.x & 31, ty = threadIdx.x >> 5;
  #pragma unroll
  for (int j = 0; j < 32; j += 8)
    t[ty + j][tx] = in[(size_t)(by + ty + j) * cols + (bx + tx)];
  __syncthreads();
  #pragma unroll
  for (int j = 0; j < 32; j += 8)
    out[(size_t)(bx + ty + j) * rows + (by + tx)] = f2bf(t[tx][ty + j]);
}

__global__ void k_prep_M(const float* __restrict__ M, short* __restrict__ Mt) {
  int idx = blockIdx.x * 256 + threadIdx.x;
  if (idx >= DOUT * DIN) return;
  int o = idx / DIN, i = idx - o * DIN;
  const float* src = M + ((size_t)o * DIN + i) * KX;
  #pragma unroll
  for (int t = 0; t < KX; ++t)
    Mt[((size_t)t * DOUT + o) * DIN + i] = f2bf(src[t]);
}

// ================= chunked scan (uB is bf16) =================
__global__ void k_scan_E(const short* __restrict__ uB, const float* __restrict__ A,
                         float* __restrict__ E) {
  int blk = blockIdx.x, tid = threadIdx.x;
  int b = blk >> 5, c = blk & 31;
  int s0 = tid * 4;
  const short* base = uB + ((size_t)b * SEQ + (size_t)c * LC) * SDIM + s0;
  float a[4], h[4];
  #pragma unroll
  for (int j = 0; j < 4; ++j) { a[j] = A[s0 + j]; h[j] = 0.f; }
  for (int t = 0; t < LC; ++t) {
    bfx4 v = *reinterpret_cast<const bfx4*>(base + (size_t)t * SDIM);
    #pragma unroll
    for (int j = 0; j < 4; ++j) h[j] = fmaf(a[j], h[j], bf2f(v[j]));
  }
  float* ep = E + (size_t)blk * SDIM + s0;
  #pragma unroll
  for (int j = 0; j < 4; ++j) ep[j] = h[j];
}

__global__ void k_scan_S(const float* __restrict__ E, const float* __restrict__ A,
                         const float* __restrict__ h0, float* __restrict__ Sb) {
  int blk = blockIdx.x, tid = threadIdx.x;
  int b = blk >> 2;
  int s = ((blk & 3) << 8) + tid;
  float a = A[s], ap = a;
  #pragma unroll
  for (int q = 0; q < 6; ++q) ap *= ap;   // a^64
  float S = h0[s];
  for (int c = 0; c < NC; ++c) {
    size_t idx = ((size_t)b * NC + c) * SDIM + s;
    Sb[idx] = S;
    S = fmaf(ap, S, E[idx]);
  }
}

__global__ void k_scan_h(const short* __restrict__ uB, const float* __restrict__ A,
                         const float* __restrict__ Sb, short* __restrict__ hs) {
  int blk = blockIdx.x, tid = threadIdx.x;
  int b = blk >> 5, c = blk & 31;
  int s0 = tid * 4;
  const short* base = uB + ((size_t)b * SEQ + (size_t)c * LC) * SDIM + s0;
  short* hbase = hs + ((size_t)b * SEQ + (size_t)c * LC) * SDIM + s0;
  float a[4], h[4];
  #pragma unroll
  for (int j = 0; j < 4; ++j) {
    a[j] = A[s0 + j];
    h[j] = Sb[(size_t)blk * SDIM + s0 + j];
  }
  for (int t = 0; t < LC; ++t) {
    bfx4 v = *reinterpret_cast<const bfx4*>(base + (size_t)t * SDIM);
    bfx4 o;
    #pragma unroll
    for (int j = 0; j < 4; ++j) {
      h[j] = fmaf(a[j], h[j], bf2f(v[j]));
      o[j] = (unsigned short)f2bf(h[j]);
    }
    *reinterpret_cast<bfx4*>(hbase + (size_t)t * SDIM) = o;
  }
}

// ================= GEMM1: m97 structure (128x128, 4 waves) — proven in R3 =====
__device__ __forceinline__ void stage32(const short* __restrict__ g0, int ld,
                                        short* l0, int w, int lane) {
  int r8 = lane >> 3;
  int slot = (lane & 7) ^ r8;
  const char* gb = (const char*)g0 + slot * 16;
  #pragma unroll
  for (int i = 0; i < 4; ++i) {
    int row = w * 32 + i * 8;
    GLOAD16(gb + ((size_t)(row + r8) * ld) * 2, l0 + row * 64);
  }
}

__device__ __forceinline__ void mfma_Ktile_swz(const short* lA, const short* lB,
                                               int lane, int wm, int wn, f32x4 acc[4][4]) {
  int lr = lane & 15;
  int h  = lane >> 4;
  #pragma unroll
  for (int kk = 0; kk < 64; kk += 32) {
    int kslot = (kk >> 3) + h;
    short8 af[4], bfr[4];
    #pragma unroll
    for (int mi = 0; mi < 4; ++mi) {
      int row = wm * 64 + mi * 16 + lr;
      af[mi] = *reinterpret_cast<const short8*>(lA + row * 64 + ((kslot ^ (row & 7)) << 3));
    }
    #pragma unroll
    for (int ni = 0; ni < 4; ++ni) {
      int row = wn * 64 + ni * 16 + lr;
      bfr[ni] = *reinterpret_cast<const short8*>(lB + row * 64 + ((kslot ^ (row & 7)) << 3));
    }
    #pragma unroll
    for (int mi = 0; mi < 4; ++mi)
      #pragma unroll
      for (int ni = 0; ni < 4; ++ni)
        acc[mi][ni] = __builtin_amdgcn_mfma_f32_16x16x32_bf16(af[mi], bfr[ni], acc[mi][ni], 0, 0, 0);
  }
}

__global__ __launch_bounds__(256) void k_gemm_uB(const short* __restrict__ Xp,
                                                 const short* __restrict__ Bt,
                                                 short* __restrict__ uB) {
  __shared__ __attribute__((aligned(16))) short lA[128 * 64];
  __shared__ __attribute__((aligned(16))) short lB[128 * 64];
  int tid = threadIdx.x, lane = tid & 63, w = tid >> 6, wm = w >> 1, wn = w & 1;
  long r0 = (long)blockIdx.x * 128;
  int  c0 = blockIdx.y * 128;
  int  b  = (int)(r0 >> 11);
  const short* Abase = Xp + (size_t)(r0 + 16 * (b + 1)) * DIN;
  const f32x4 z4 = {0.f, 0.f, 0.f, 0.f};
  f32x4 acc[4][4];
  #pragma unroll
  for (int mi = 0; mi < 4; ++mi)
    #pragma unroll
    for (int ni = 0; ni < 4; ++ni) acc[mi][ni] = z4;

  for (int k0 = 0; k0 < DIN; k0 += 64) {
    stage32(Abase + k0, DIN, lA, w, lane);
    stage32(Bt + (size_t)c0 * DIN + k0, DIN, lB, w, lane);
    __syncthreads();
    mfma_Ktile_swz(lA, lB, lane, wm, wn, acc);
    __syncthreads();
  }
  #pragma unroll
  for (int mi = 0; mi < 4; ++mi)
    #pragma unroll
    for (int ni = 0; ni < 4; ++ni)
      #pragma unroll
      for (int r = 0; r < 4; ++r) {
        long row = r0 + wm * 64 + mi * 16 + (lane >> 4) * 4 + r;
        int  col = c0 + wn * 64 + ni * 16 + (lane & 15);
        uB[(size_t)row * SDIM + col] = f2bf(acc[mi][ni][r]);
      }
}

// ================= GEMM2: 256x128 tile, 8 waves, dbuf + counted vmcnt =========
// K linearized into 96 tiles of 64: kt<16 -> hs@Ct (K=1024); else tap segments.
#define NKT   96
#define ABUF  (256 * 64)           // shorts
#define BBUF  (128 * 64)
#define BUFSZ (ABUF + BBUF)        // 24576 shorts = 48 KiB

__device__ __forceinline__ void tile_ptrs(int kt, long r0, int c0, int b,
                                          const short* __restrict__ hs,
                                          const short* __restrict__ Xp,
                                          const short* __restrict__ Ct,
                                          const short* __restrict__ Mt,
                                          const short** pA, const short** pB, int* ld) {
  if (kt < 16) {
    *pA = hs + (size_t)r0 * SDIM + kt * 64;
    *pB = Ct + (size_t)c0 * SDIM + kt * 64;
    *ld = SDIM;
  } else {
    int t = kt - 16;
    int tap = t >> 3;
    int k0 = (t & 7) * 64;
    *pA = Xp + (size_t)(r0 + 16 * (b + 1) - tap) * DIN + k0;
    *pB = Mt + (size_t)tap * DOUT * DIN + (size_t)c0 * DIN + k0;
    *ld = DIN;
  }
}

// 512 threads stage A(256x64) + B(128x64), swizzled source, linear LDS dest.
__device__ __forceinline__ void stage_tile(const short* __restrict__ pA,
                                           const short* __restrict__ pB, int ld,
                                           short* buf, int tid) {
  int rsub = tid >> 3;                      // 0..63
  int slot = (tid & 7) ^ (rsub & 7);        // pre-swizzled 16B slot
  short* la = buf;
  short* lb = buf + ABUF;
  #pragma unroll
  for (int i = 0; i < 4; ++i) {             // A: 4 rounds of 64 rows
    int row = i * 64 + rsub;
    GLOAD16(pA + (size_t)row * ld + slot * 8, la + row * 64 + (tid & 7) * 8);
  }
  #pragma unroll
  for (int i = 0; i < 2; ++i) {             // B: 2 rounds
    int row = i * 64 + rsub;
    GLOAD16(pB + (size_t)row * ld + slot * 8, lb + row * 64 + (tid & 7) * 8);
  }
}

__device__ __forceinline__ void compute_tile(const short* la, const short* lb,
                                             int lane, int wm, int wn, f32x4 acc[4][4]) {
  int lr = lane & 15;
  int h  = lane >> 4;
  #pragma unroll
  for (int kk = 0; kk < 64; kk += 32) {
    int kslot = (kk >> 3) + h;
    short8 af[4], bfr[4];
    #pragma unroll
    for (int mi = 0; mi < 4; ++mi) {
      int row = wm * 64 + mi * 16 + lr;
      af[mi] = *reinterpret_cast<const short8*>(la + row * 64 + ((kslot ^ (row & 7)) << 3));
    }
    #pragma unroll
    for (int ni = 0; ni < 4; ++ni) {
      int row = wn * 64 + ni * 16 + lr;
      bfr[ni] = *reinterpret_cast<const short8*>(lb + row * 64 + ((kslot ^ (row & 7)) << 3));
    }
    __builtin_amdgcn_s_setprio(1);
    #pragma unroll
    for (int mi = 0; mi < 4; ++mi)
      #pragma unroll
      for (int ni = 0; ni < 4; ++ni)
        acc[mi][ni] = __builtin_amdgcn_mfma_f32_16x16x32_bf16(af[mi], bfr[ni], acc[mi][ni], 0, 0, 0);
    __builtin_amdgcn_s_setprio(0);
  }
}

__global__ __launch_bounds__(512) void k_gemm_out(const short* __restrict__ hs,
                                                  const short* __restrict__ Xp,
                                                  const short* __restrict__ Ct,
                                                  const short* __restrict__ Mt,
                                                  float* __restrict__ out) {
  __shared__ __attribute__((aligned(16))) short lds[2][BUFSZ];
  int tid = threadIdx.x, lane = tid & 63, w = tid >> 6;
  int wm = w >> 1, wn = w & 1;                 // 4M x 2N wave grid, 64x64 each
  // XCD-bijective swizzle: XCD k owns 32 consecutive sw ids -> one B col-panel
  int bid = blockIdx.x;
  int sw  = (bid & 7) * 32 + (bid >> 3);       // 256 = 8 * 32, bijective
  long r0 = (long)(sw & 63) * 256;
  int  c0 = (sw >> 6) * 128;
  int  b  = (int)(r0 >> 11);

  const f32x4 z4 = {0.f, 0.f, 0.f, 0.f};
  f32x4 acc[4][4];
  #pragma unroll
  for (int mi = 0; mi < 4; ++mi)
    #pragma unroll
    for (int ni = 0; ni < 4; ++ni) acc[mi][ni] = z4;

  const short *pA, *pB; int ld;
  // prologue: stage tiles 0 and 1
  tile_ptrs(0, r0, c0, b, hs, Xp, Ct, Mt, &pA, &pB, &ld);
  stage_tile(pA, pB, ld, lds[0], tid);
  tile_ptrs(1, r0, c0, b, hs, Xp, Ct, Mt, &pA, &pB, &ld);
  stage_tile(pA, pB, ld, lds[1], tid);
  asm volatile("s_waitcnt vmcnt(6)" ::: "memory");   // tile 0 landed
  __builtin_amdgcn_s_barrier();

  for (int kt = 0; kt < NKT; ++kt) {
    short* cur = lds[kt & 1];
    compute_tile(cur, cur + ABUF, lane, wm, wn, acc);
    __builtin_amdgcn_s_barrier();                    // all waves done reading cur
    if (kt + 2 < NKT) {
      tile_ptrs(kt + 2, r0, c0, b, hs, Xp, Ct, Mt, &pA, &pB, &ld);
      stage_tile(pA, pB, ld, cur, tid);              // refill freed buffer
      asm volatile("s_waitcnt vmcnt(6)" ::: "memory"); // tile kt+1 landed; kt+2 in flight
    } else {
      asm volatile("s_waitcnt vmcnt(0)" ::: "memory"); // tail: drain
    }
    __builtin_amdgcn_s_barrier();
  }

  #pragma unroll
  for (int mi = 0; mi < 4; ++mi)
    #pragma unroll
    for (int ni = 0; ni < 4; ++ni)
      #pragma unroll
      for (int r = 0; r < 4; ++r) {
        long row = r0 + wm * 64 + mi * 16 + (lane >> 4) * 4 + r;
        int  col = c0 + wn * 64 + ni * 16 + (lane & 15);
        out[(size_t)row * DOUT + col] = acc[mi][ni][r];
      }
}

// ================= launch =================
extern "C" void kernel_launch(void* const* d_in, const int* in_sizes, int n_in,
                              void* d_out, int out_size, void* d_ws, size_t ws_size,
                              hipStream_t stream) {
  (void)in_sizes; (void)n_in; (void)out_size; (void)ws_size;
  const float* x  = (const float*)d_in[0];
  const float* h0 = (const float*)d_in[1];
  const float* A  = (const float*)d_in[2];
  const float* B  = (const float*)d_in[3];
  const float* C  = (const float*)d_in[4];
  const float* M  = (const float*)d_in[5];
  float* out = (float*)d_out;
  char* ws = (char*)d_ws;

  short* Xp  = (short*)(ws + OFF_XP);
  short* uB  = (short*)(ws + OFF_UB);
  short* hsb = (short*)(ws + OFF_HS);
  short* Bt  = (short*)(ws + OFF_BT);
  short* Ct  = (short*)(ws + OFF_CT);
  short* Mt  = (short*)(ws + OFF_MT);
  // scan scratch inside d_out (fully overwritten by k_gemm_out afterwards)
  float* E   = out;                    // B_SZ*NC*SDIM f32 = 1 MiB
  float* Sb  = out + B_SZ * NC * SDIM; // 1 MiB

  k_conv_x<<<2048, 256, 0, stream>>>(x, Xp);
  k_zero_pad<<<32, 256, 0, stream>>>(Xp);
  k_transpose_bf16<<<dim3(SDIM / 32, DIN / 32), 256, 0, stream>>>(B, Bt, DIN, SDIM);
  k_transpose_bf16<<<dim3(DOUT / 32, SDIM / 32), 256, 0, stream>>>(C, Ct, SDIM, DOUT);
  k_prep_M<<<(DOUT * DIN + 255) / 256, 256, 0, stream>>>(M, Mt);

  k_gemm_uB<<<dim3(RTOT / 128, SDIM / 128), 256, 0, stream>>>(Xp, Bt, uB);

  k_scan_E<<<B_SZ * NC, 256, 0, stream>>>(uB, A, E);
  k_scan_S<<<B_SZ * 4, 256, 0, stream>>>(E, A, h0, Sb);
  k_scan_h<<<B_SZ * NC, 256, 0, stream>>>(uB, A, Sb, hsb);

  k_gemm_out<<<256, 512, 0, stream>>>(hsb, Xp, Ct, Mt, out);
}

// Round 5
// 156.017 us; speedup vs baseline: 1.2026x; 1.2026x over previous
//
#include <hip/hip_runtime.h>

#define B_SZ   8
#define SEQ    2048
#define PSEQ   (SEQ+16)     // 16 zero pad rows before each batch
#define SDIM   1024
#define DIN    512
#define DOUT   512
#define KX     10
#define RTOT   (B_SZ*SEQ)   // 16384
#define LC     64
#define NC     (SEQ/LC)     // 32

typedef __attribute__((ext_vector_type(8))) short short8;
typedef __attribute__((ext_vector_type(4))) float f32x4;
typedef __attribute__((ext_vector_type(4))) unsigned short bfx4;

// ---- workspace layout (bytes) ----
#define OFF_XP   0UL             // B_SZ*PSEQ*DIN*2      = 16,908,288
#define OFF_UB   16908288UL      // RTOT*SDIM*2 (bf16)   = 33,554,432
#define OFF_HS   50462720UL      // RTOT*SDIM*2 (bf16)   = 33,554,432
#define OFF_BT   84017152UL      // SDIM*DIN*2           = 1,048,576
#define OFF_CT   85065728UL      // DOUT*SDIM*2          = 1,048,576
#define OFF_MT   86114304UL      // KX*DOUT*DIN*2        = 5,242,880

__device__ __forceinline__ short f2bf(float f) {
  unsigned u = __builtin_bit_cast(unsigned, f);
  u += 0x7fffu + ((u >> 16) & 1u);   // RNE
  return (short)(u >> 16);
}
__device__ __forceinline__ float bf2f(unsigned short b) {
  return __builtin_bit_cast(float, (unsigned)b << 16);
}

#define GLOAD16(gp, lp) __builtin_amdgcn_global_load_lds( \
    (const __attribute__((address_space(1))) void*)(gp), \
    (__attribute__((address_space(3))) void*)(lp), 16, 0, 0)
#define WAITVM(n) asm volatile("s_waitcnt vmcnt(" #n ")" ::: "memory")
#define SBAR() __builtin_amdgcn_s_barrier()

// ================= conversion / prep =================
__global__ void k_conv_x(const float* __restrict__ in, short* __restrict__ out) {
  const int NG = RTOT * (DIN / 8);
  for (int g = blockIdx.x * 256 + threadIdx.x; g < NG; g += 2048 * 256) {
    int r = g >> 6, c8 = g & 63;
    int b = r >> 11, t = r & 2047;
    const float4* p = reinterpret_cast<const float4*>(in) + (size_t)g * 2;
    float4 f0 = p[0], f1 = p[1];
    short8 o;
    o[0]=f2bf(f0.x); o[1]=f2bf(f0.y); o[2]=f2bf(f0.z); o[3]=f2bf(f0.w);
    o[4]=f2bf(f1.x); o[5]=f2bf(f1.y); o[6]=f2bf(f1.z); o[7]=f2bf(f1.w);
    *reinterpret_cast<short8*>(out + ((size_t)(b * PSEQ + 16 + t) * DIN + c8 * 8)) = o;
  }
}

__global__ void k_zero_pad(short* __restrict__ Xp) {
  int idx = blockIdx.x * 256 + threadIdx.x;
  if (idx >= B_SZ * 16 * (DIN / 8)) return;
  int b = idx >> 10, rem = idx & 1023;
  int row16 = rem >> 6, c8 = rem & 63;
  const short8 z = {0,0,0,0,0,0,0,0};
  *reinterpret_cast<short8*>(Xp + ((size_t)(b * PSEQ + row16) * DIN + c8 * 8)) = z;
}

__global__ void k_transpose_bf16(const float* __restrict__ in, short* __restrict__ out,
                                 int rows, int cols) {
  __shared__ float t[32][33];
  int bx = blockIdx.x * 32, by = blockIdx.y * 32;
  int tx = threadIdx.x & 31, ty = threadIdx.x >> 5;
  #pragma unroll
  for (int j = 0; j < 32; j += 8)
    t[ty + j][tx] = in[(size_t)(by + ty + j) * cols + (bx + tx)];
  __syncthreads();
  #pragma unroll
  for (int j = 0; j < 32; j += 8)
    out[(size_t)(bx + ty + j) * rows + (by + tx)] = f2bf(t[tx][ty + j]);
}

__global__ void k_prep_M(const float* __restrict__ M, short* __restrict__ Mt) {
  int idx = blockIdx.x * 256 + threadIdx.x;
  if (idx >= DOUT * DIN) return;
  int o = idx / DIN, i = idx - o * DIN;
  const float* src = M + ((size_t)o * DIN + i) * KX;
  #pragma unroll
  for (int t = 0; t < KX; ++t)
    Mt[((size_t)t * DOUT + o) * DIN + i] = f2bf(src[t]);
}

// ================= chunked scan (uB is bf16) =================
__global__ void k_scan_E(const short* __restrict__ uB, const float* __restrict__ A,
                         float* __restrict__ E) {
  int blk = blockIdx.x, tid = threadIdx.x;
  int b = blk >> 5, c = blk & 31;
  int s0 = tid * 4;
  const short* base = uB + ((size_t)b * SEQ + (size_t)c * LC) * SDIM + s0;
  float a[4], h[4];
  #pragma unroll
  for (int j = 0; j < 4; ++j) { a[j] = A[s0 + j]; h[j] = 0.f; }
  for (int t = 0; t < LC; ++t) {
    bfx4 v = *reinterpret_cast<const bfx4*>(base + (size_t)t * SDIM);
    #pragma unroll
    for (int j = 0; j < 4; ++j) h[j] = fmaf(a[j], h[j], bf2f(v[j]));
  }
  float* ep = E + (size_t)blk * SDIM + s0;
  #pragma unroll
  for (int j = 0; j < 4; ++j) ep[j] = h[j];
}

__global__ void k_scan_S(const float* __restrict__ E, const float* __restrict__ A,
                         const float* __restrict__ h0, float* __restrict__ Sb) {
  int blk = blockIdx.x, tid = threadIdx.x;
  int b = blk >> 2;
  int s = ((blk & 3) << 8) + tid;
  float a = A[s], ap = a;
  #pragma unroll
  for (int q = 0; q < 6; ++q) ap *= ap;   // a^64
  float S = h0[s];
  for (int c = 0; c < NC; ++c) {
    size_t idx = ((size_t)b * NC + c) * SDIM + s;
    Sb[idx] = S;
    S = fmaf(ap, S, E[idx]);
  }
}

__global__ void k_scan_h(const short* __restrict__ uB, const float* __restrict__ A,
                         const float* __restrict__ Sb, short* __restrict__ hs) {
  int blk = blockIdx.x, tid = threadIdx.x;
  int b = blk >> 5, c = blk & 31;
  int s0 = tid * 4;
  const short* base = uB + ((size_t)b * SEQ + (size_t)c * LC) * SDIM + s0;
  short* hbase = hs + ((size_t)b * SEQ + (size_t)c * LC) * SDIM + s0;
  float a[4], h[4];
  #pragma unroll
  for (int j = 0; j < 4; ++j) {
    a[j] = A[s0 + j];
    h[j] = Sb[(size_t)blk * SDIM + s0 + j];
  }
  for (int t = 0; t < LC; ++t) {
    bfx4 v = *reinterpret_cast<const bfx4*>(base + (size_t)t * SDIM);
    bfx4 o;
    #pragma unroll
    for (int j = 0; j < 4; ++j) {
      h[j] = fmaf(a[j], h[j], bf2f(v[j]));
      o[j] = (unsigned short)f2bf(h[j]);
    }
    *reinterpret_cast<bfx4*>(hbase + (size_t)t * SDIM) = o;
  }
}

// ================= shared GEMM building blocks =================
// LDS tile [rows][64] bf16 linear. 16B-slot s of row r holds global slot s^(r&7).
// stage128: 256 threads stage a 128x64 tile (4 gload_lds each).
__device__ __forceinline__ void stage128(const short* __restrict__ g, int ld,
                                         short* l, int tid) {
  int rsub = tid >> 3;                    // 0..31
  int slot = (tid & 7) ^ (rsub & 7);      // pre-swizzled 16B slot
  #pragma unroll
  for (int i = 0; i < 4; ++i) {
    int row = i * 32 + rsub;
    GLOAD16(g + (size_t)row * ld + slot * 8, l + row * 64 + (tid & 7) * 8);
  }
}
// stage144: 128x64 + 16 extra rows (waves 0,1 only on the tail round)
__device__ __forceinline__ void stage144(const short* __restrict__ g, int ld,
                                         short* l, int tid) {
  stage128(g, ld, l, tid);
  if (tid < 128) {
    int rsub = tid >> 3;                  // 0..15
    int slot = (tid & 7) ^ (rsub & 7);
    int row = 128 + rsub;
    GLOAD16(g + (size_t)row * ld + slot * 8, l + row * 64 + (tid & 7) * 8);
  }
}

// One K=64 tile of MFMAs. aoff = extra LDS-row offset for A (AR tap shifts).
__device__ __forceinline__ void mfma_tile(const short* lA, int aoff, const short* lB,
                                          int lane, int wm, int wn, f32x4 acc[4][4]) {
  int lr = lane & 15;
  int h  = lane >> 4;
  #pragma unroll
  for (int kk = 0; kk < 2; ++kk) {
    int kslot = kk * 4 + h;
    short8 af[4], bfr[4];
    #pragma unroll
    for (int mi = 0; mi < 4; ++mi) {
      int row = aoff + wm * 64 + mi * 16 + lr;
      af[mi] = *reinterpret_cast<const short8*>(lA + row * 64 + ((kslot ^ (row & 7)) << 3));
    }
    #pragma unroll
    for (int ni = 0; ni < 4; ++ni) {
      int row = wn * 64 + ni * 16 + lr;
      bfr[ni] = *reinterpret_cast<const short8*>(lB + row * 64 + ((kslot ^ (row & 7)) << 3));
    }
    __builtin_amdgcn_s_setprio(1);
    #pragma unroll
    for (int mi = 0; mi < 4; ++mi)
      #pragma unroll
      for (int ni = 0; ni < 4; ++ni)
        acc[mi][ni] = __builtin_amdgcn_mfma_f32_16x16x32_bf16(af[mi], bfr[ni], acc[mi][ni], 0, 0, 0);
    __builtin_amdgcn_s_setprio(0);
  }
}

// ================= GEMM1: uB = Xrows @ Bt^T (dbuf + counted vmcnt) =========
__global__ __launch_bounds__(256) void k_gemm_uB(const short* __restrict__ Xp,
                                                 const short* __restrict__ Bt,
                                                 short* __restrict__ uB) {
  __shared__ __attribute__((aligned(16))) short lds[32768];
  short* A0 = lds;         short* B0 = lds + 8192;
  short* A1 = lds + 16384; short* B1 = lds + 24576;
  int tid = threadIdx.x, lane = tid & 63, w = tid >> 6, wm = w >> 1, wn = w & 1;
  long r0 = (long)blockIdx.x * 128;
  int  c0 = blockIdx.y * 128;
  int  b  = (int)(r0 >> 11);
  const short* Abase = Xp + (size_t)(r0 + 16 * (b + 1)) * DIN;
  const short* Bbase = Bt + (size_t)c0 * DIN;
  const f32x4 z4 = {0.f, 0.f, 0.f, 0.f};
  f32x4 acc[4][4];
  #pragma unroll
  for (int mi = 0; mi < 4; ++mi)
    #pragma unroll
    for (int ni = 0; ni < 4; ++ni) acc[mi][ni] = z4;

  stage128(Abase, DIN, A0, tid);      stage128(Bbase, DIN, B0, tid);
  stage128(Abase + 64, DIN, A1, tid); stage128(Bbase + 64, DIN, B1, tid);
  WAITVM(8);
  SBAR();
  for (int kt = 0; kt < 8; ++kt) {
    const short* a  = (kt & 1) ? A1 : A0;
    const short* bb = (kt & 1) ? B1 : B0;
    mfma_tile(a, 0, bb, lane, wm, wn, acc);
    SBAR();
    if (kt + 2 < 8) {
      short* ad = (kt & 1) ? A1 : A0;
      short* bd = (kt & 1) ? B1 : B0;
      stage128(Abase + (kt + 2) * 64, DIN, ad, tid);
      stage128(Bbase + (kt + 2) * 64, DIN, bd, tid);
      WAITVM(8);
    } else {
      WAITVM(0);
    }
    SBAR();
  }
  #pragma unroll
  for (int mi = 0; mi < 4; ++mi)
    #pragma unroll
    for (int ni = 0; ni < 4; ++ni)
      #pragma unroll
      for (int r = 0; r < 4; ++r) {
        long row = r0 + wm * 64 + mi * 16 + (lane >> 4) * 4 + r;
        int  col = c0 + wn * 64 + ni * 16 + (lane & 15);
        uB[(size_t)row * SDIM + col] = f2bf(acc[mi][ni][r]);
      }
}

// ================= GEMM2: out = hs@Ct^T + conv(X)@Mt^T ======================
// Phase 1 (16 K-tiles): dbuf hs/Ct, counted vmcnt(8).
// Phase 2 (8 k0-slices): Xs[144][64] staged ONCE, reused by all 10 taps;
//                        Mt slices double-buffered, counted vmcnt(4).
__global__ __launch_bounds__(256) void k_gemm_out(const short* __restrict__ hs,
                                                  const short* __restrict__ Xp,
                                                  const short* __restrict__ Ct,
                                                  const short* __restrict__ Mt,
                                                  float* __restrict__ out) {
  __shared__ __attribute__((aligned(16))) short lds[32768];
  short* A0 = lds;         short* B0 = lds + 8192;
  short* A1 = lds + 16384; short* B1 = lds + 24576;
  short* Xs = lds;                       // 144*64 = 9216 shorts (A0 + head of B0)
  short* M0 = lds + 16384;               // reuse A1
  short* M1 = lds + 24576;               // reuse B1
  int tid = threadIdx.x, lane = tid & 63, w = tid >> 6, wm = w >> 1, wn = w & 1;
  long r0 = (long)blockIdx.x * 128;
  int  c0 = blockIdx.y * 128;
  int  b  = (int)(r0 >> 11);
  const short* hsA = hs + (size_t)r0 * SDIM;
  const short* CtB = Ct + (size_t)c0 * SDIM;
  const short* Xa  = Xp + (size_t)(r0 + 16 * (b + 1) - 16) * DIN;  // LDS row j <-> Xp row r0p-16+j
  const f32x4 z4 = {0.f, 0.f, 0.f, 0.f};
  f32x4 acc[4][4];
  #pragma unroll
  for (int mi = 0; mi < 4; ++mi)
    #pragma unroll
    for (int ni = 0; ni < 4; ++ni) acc[mi][ni] = z4;

  // ---- phase 1: hs @ Ct^T (K = 1024) ----
  stage128(hsA, SDIM, A0, tid);      stage128(CtB, SDIM, B0, tid);
  stage128(hsA + 64, SDIM, A1, tid); stage128(CtB + 64, SDIM, B1, tid);
  WAITVM(8);
  SBAR();
  for (int kt = 0; kt < 16; ++kt) {
    const short* a  = (kt & 1) ? A1 : A0;
    const short* bb = (kt & 1) ? B1 : B0;
    mfma_tile(a, 0, bb, lane, wm, wn, acc);
    SBAR();
    if (kt + 2 < 16) {
      short* ad = (kt & 1) ? A1 : A0;
      short* bd = (kt & 1) ? B1 : B0;
      stage128(hsA + (kt + 2) * 64, SDIM, ad, tid);
      stage128(CtB + (kt + 2) * 64, SDIM, bd, tid);
      WAITVM(8);
    } else {
      WAITVM(0);
    }
    SBAR();
  }

  // ---- phase 2: AR conv, X staged once per k0-slice ----
  for (int k0 = 0; k0 < 8; ++k0) {
    int kc = k0 * 64;
    stage144(Xa + kc, DIN, Xs, tid);                                   // 5 (or 4) loads
    stage128(Mt + (size_t)c0 * DIN + kc, DIN, M0, tid);                // tap 0
    stage128(Mt + (size_t)DOUT * DIN + (size_t)c0 * DIN + kc, DIN, M1, tid); // tap 1
    WAITVM(4);        // Xs + M0 landed; M1's 4 in flight
    SBAR();
    for (int tap = 0; tap < KX; ++tap) {
      const short* mb = (tap & 1) ? M1 : M0;
      mfma_tile(Xs, 16 - tap, mb, lane, wm, wn, acc);
      SBAR();
      if (tap + 2 < KX) {
        short* md = (tap & 1) ? M1 : M0;
        stage128(Mt + (size_t)(tap + 2) * DOUT * DIN + (size_t)c0 * DIN + kc, DIN, md, tid);
        WAITVM(4);
      } else {
        WAITVM(0);
      }
      SBAR();
    }
  }

  #pragma unroll
  for (int mi = 0; mi < 4; ++mi)
    #pragma unroll
    for (int ni = 0; ni < 4; ++ni)
      #pragma unroll
      for (int r = 0; r < 4; ++r) {
        long row = r0 + wm * 64 + mi * 16 + (lane >> 4) * 4 + r;
        int  col = c0 + wn * 64 + ni * 16 + (lane & 15);
        out[(size_t)row * DOUT + col] = acc[mi][ni][r];
      }
}

// ================= launch =================
extern "C" void kernel_launch(void* const* d_in, const int* in_sizes, int n_in,
                              void* d_out, int out_size, void* d_ws, size_t ws_size,
                              hipStream_t stream) {
  (void)in_sizes; (void)n_in; (void)out_size; (void)ws_size;
  const float* x  = (const float*)d_in[0];
  const float* h0 = (const float*)d_in[1];
  const float* A  = (const float*)d_in[2];
  const float* B  = (const float*)d_in[3];
  const float* C  = (const float*)d_in[4];
  const float* M  = (const float*)d_in[5];
  float* out = (float*)d_out;
  char* ws = (char*)d_ws;

  short* Xp  = (short*)(ws + OFF_XP);
  short* uB  = (short*)(ws + OFF_UB);
  short* hsb = (short*)(ws + OFF_HS);
  short* Bt  = (short*)(ws + OFF_BT);
  short* Ct  = (short*)(ws + OFF_CT);
  short* Mt  = (short*)(ws + OFF_MT);
  // scan scratch inside d_out (fully overwritten by k_gemm_out afterwards)
  float* E   = out;                    // B_SZ*NC*SDIM f32 = 1 MiB
  float* Sb  = out + B_SZ * NC * SDIM; // 1 MiB

  k_conv_x<<<2048, 256, 0, stream>>>(x, Xp);
  k_zero_pad<<<32, 256, 0, stream>>>(Xp);
  k_transpose_bf16<<<dim3(SDIM / 32, DIN / 32), 256, 0, stream>>>(B, Bt, DIN, SDIM);
  k_transpose_bf16<<<dim3(DOUT / 32, SDIM / 32), 256, 0, stream>>>(C, Ct, SDIM, DOUT);
  k_prep_M<<<(DOUT * DIN + 255) / 256, 256, 0, stream>>>(M, Mt);

  k_gemm_uB<<<dim3(RTOT / 128, SDIM / 128), 256, 0, stream>>>(Xp, Bt, uB);

  k_scan_E<<<B_SZ * NC, 256, 0, stream>>>(uB, A, E);
  k_scan_S<<<B_SZ * 4, 256, 0, stream>>>(E, A, h0, Sb);
  k_scan_h<<<B_SZ * NC, 256, 0, stream>>>(uB, A, Sb, hsb);

  k_gemm_out<<<dim3(RTOT / 128, DOUT / 128), 256, 0, stream>>>(hsb, Xp, Ct, Mt, out);
}